// Round 4
// baseline (1222.736 us; speedup 1.0000x reference)
//
#include <hip/hip_runtime.h>
#include <hip/hip_bf16.h>

typedef unsigned short u16;
typedef __attribute__((ext_vector_type(8))) __bf16 bf16x8;
typedef __attribute__((ext_vector_type(4))) float f32x4;

#define LDSS 40  // LDS row stride in bf16 elems (32 data + 8 pad): 16B-aligned, max 2-way bank aliasing

__device__ __forceinline__ float bf2f(u16 u) {
    unsigned int x = ((unsigned int)u) << 16;
    return __builtin_bit_cast(float, x);
}
__device__ __forceinline__ u16 f2bf(float f) {
    unsigned int x = __builtin_bit_cast(unsigned int, f);
    unsigned int lsb = (x >> 16) & 1u;
    x += 0x7fffu + lsb;
    return (u16)(x >> 16);
}

// --- staging: load 8 contiguous elems from global, store 8 bf16 to LDS ------
__device__ __forceinline__ void ld8(u16* dst, const u16* src) {
    *(float4*)dst = *(const float4*)src;
}
__device__ __forceinline__ void ld8(u16* dst, const float* src) {
    float4 a = *(const float4*)src;
    float4 b = *(const float4*)(src + 4);
    u16 t[8];
    t[0] = f2bf(a.x); t[1] = f2bf(a.y); t[2] = f2bf(a.z); t[3] = f2bf(a.w);
    t[4] = f2bf(b.x); t[5] = f2bf(b.y); t[6] = f2bf(b.z); t[7] = f2bf(b.w);
    *(float4*)dst = *(float4*)t;
}
__device__ __forceinline__ void stC(u16* p, float v)   { *p = f2bf(v); }
__device__ __forceinline__ void stC(float* p, float v) { *p = v; }

// ---------------------------------------------------------------------------
// Generic NT GEMM: C[m,n] = sum_k A[m,k]*B[n,k] (+ bias[n]), fp32 acc.
// Grid: (Nn/128, M/128, batch). Block: 256 threads (4 waves, 2x2 of 64x64).
// ---------------------------------------------------------------------------
template <typename TA, typename TB, typename TC>
__global__ __launch_bounds__(256)
void gemm_nt(const TA* __restrict__ A, long long sA, int lda,
             const TB* __restrict__ B, long long sB, int ldb,
             TC* __restrict__ C, long long sC, int ldc,
             const float* __restrict__ bias, int K)
{
    __shared__ u16 As[128 * LDSS];
    __shared__ u16 Bs[128 * LDSS];

    const int tid = threadIdx.x;
    const int z = blockIdx.z;
    A += (long long)z * sA;
    B += (long long)z * sB;
    C += (long long)z * sC;
    const int m0 = blockIdx.y * 128;
    const int n0 = blockIdx.x * 128;
    const int wid = tid >> 6;
    const int lane = tid & 63;
    const int wm = (wid >> 1) * 64;
    const int wn = (wid & 1) * 64;
    const int lr = lane & 15;
    const int quad = lane >> 4;

    f32x4 acc[4][4];
#pragma unroll
    for (int i = 0; i < 4; i++)
#pragma unroll
        for (int j = 0; j < 4; j++)
#pragma unroll
            for (int r = 0; r < 4; r++) acc[i][j][r] = 0.f;

    const int srow = tid >> 2;          // 0..63
    const int scol = (tid & 3) * 8;     // 0,8,16,24

    for (int k0 = 0; k0 < K; k0 += 32) {
        __syncthreads();
        const TA* ga = A + (long long)(m0 + srow) * lda + k0 + scol;
        ld8(&As[srow * LDSS + scol], ga);
        ld8(&As[(srow + 64) * LDSS + scol], ga + (long long)64 * lda);
        const TB* gb = B + (long long)(n0 + srow) * ldb + k0 + scol;
        ld8(&Bs[srow * LDSS + scol], gb);
        ld8(&Bs[(srow + 64) * LDSS + scol], gb + (long long)64 * ldb);
        __syncthreads();

        bf16x8 af[4], bfr[4];
#pragma unroll
        for (int t = 0; t < 4; t++) {
            af[t]  = *(const bf16x8*)&As[(wm + t * 16 + lr) * LDSS + quad * 8];
            bfr[t] = *(const bf16x8*)&Bs[(wn + t * 16 + lr) * LDSS + quad * 8];
        }
#pragma unroll
        for (int i = 0; i < 4; i++)
#pragma unroll
            for (int j = 0; j < 4; j++)
                acc[i][j] = __builtin_amdgcn_mfma_f32_16x16x32_bf16(af[i], bfr[j], acc[i][j], 0, 0, 0);
    }

#pragma unroll
    for (int j = 0; j < 4; j++) {
        const int col = n0 + wn + j * 16 + lr;
        const float bv = bias ? bias[col] : 0.f;
#pragma unroll
        for (int i = 0; i < 4; i++) {
            const int rbase = m0 + wm + i * 16 + quad * 4;
#pragma unroll
            for (int r = 0; r < 4; r++)
                stC(&C[(long long)(rbase + r) * ldc + col], acc[i][j][r] + bv);
        }
    }
}

// ---------------------------------------------------------------------------
// Reorder y[B*N, 3*C] (bf16) -> q(scaled)/k/v as [B,H,N,HD], bf16.
// ---------------------------------------------------------------------------
__global__ __launch_bounds__(256)
void reorder_qkv(const u16* __restrict__ y, u16* __restrict__ q,
                 u16* __restrict__ k, u16* __restrict__ v)
{
    int t = blockIdx.x * 256 + threadIdx.x;
    int which = t >> 19;
    int r = t & 524287;
    int d8 = r & 7;
    int n = (r >> 3) & 1023;
    int h = (r >> 13) & 15;
    int b = r >> 17;
    const u16* src = y + ((long long)(b * 1024 + n)) * 3072 + which * 1024 + h * 64 + d8 * 8;
    u16* dst = (which == 0 ? q : (which == 1 ? k : v)) +
               (((long long)((b * 16 + h) * 1024 + n)) * 64 + d8 * 8);
    float4 val = *(const float4*)src;
    if (which == 0) {
        u16 tmp[8];
        *(float4*)tmp = val;
#pragma unroll
        for (int i = 0; i < 8; i++) tmp[i] = f2bf(bf2f(tmp[i]) * 0.125f);  // HD^-0.5, exact pow2
        val = *(float4*)tmp;
    }
    *(float4*)dst = val;
}

// ---------------------------------------------------------------------------
// Talking-heads mix (pre) + softmax + mix (post). One block (512 thr) per (b,n).
// Thread t owns m = 2t..2t+1; all 16 heads in registers (sv[16][2], a[16][2]).
// __launch_bounds__(512,4): cap VGPR at 128 -> 4 waves/SIMD (2 blocks/CU).
// S bf16 [B,H,N,N]; writes fp32 attn (d_out) and bf16 attn IN PLACE over S
// (safe: each (h,n,m) location read & written by the same thread, read first).
// ---------------------------------------------------------------------------
__global__ __launch_bounds__(512, 4)
void mix_softmax(const u16* __restrict__ S, float* __restrict__ attn_out,
                 u16* __restrict__ attn_bf,
                 const float* __restrict__ wl, const float* __restrict__ bl,
                 const float* __restrict__ ww, const float* __restrict__ bw)
{
    __shared__ float wlS[256];
    __shared__ float wwS[256];
    __shared__ float blS[16];
    __shared__ float bwS[16];
    __shared__ float red[128];
    __shared__ float gmax[16];
    __shared__ float gsum[16];

    const int tid = threadIdx.x;
    const int lane = tid & 63;
    const int wid = tid >> 6;        // 0..7
    const int b = blockIdx.x >> 10, n = blockIdx.x & 1023;
    const int m0 = tid * 2;

    if (tid < 256) wlS[tid] = wl[tid];
    if (tid < 16) { blS[tid] = bl[tid]; bwS[tid] = bw[tid]; }

    // load S[h, n, m0..m0+1] for all 16 h (4B coalesced per h)
    const long long base = ((long long)(b * 16) * 1024 + n) * 1024 + m0;
    float2 sv[16];
#pragma unroll
    for (int h = 0; h < 16; h++) {
        ushort2 r = *(const ushort2*)(S + base + (long long)h * 1048576);
        sv[h].x = bf2f(r.x); sv[h].y = bf2f(r.y);
    }
    __syncthreads();

    // pre-mix: a[g] = bl[g] + sum_h wl[g,h] * sv[h]   (float2 over the 2 m's)
    float2 a[16];
#pragma unroll
    for (int g = 0; g < 16; g++) {
        float wr[16];
        *(float4*)&wr[0]  = *(const float4*)&wlS[g * 16];
        *(float4*)&wr[4]  = *(const float4*)&wlS[g * 16 + 4];
        *(float4*)&wr[8]  = *(const float4*)&wlS[g * 16 + 8];
        *(float4*)&wr[12] = *(const float4*)&wlS[g * 16 + 12];
        float2 acc; acc.x = blS[g]; acc.y = blS[g];
#pragma unroll
        for (int h = 0; h < 16; h++) {
            acc.x += wr[h] * sv[h].x;
            acc.y += wr[h] * sv[h].y;
        }
        a[g] = acc;
    }

    // per-head max across block (wave shuffle -> LDS -> scalar combine)
#pragma unroll
    for (int g = 0; g < 16; g++) {
        float vv = fmaxf(a[g].x, a[g].y);
        for (int off = 32; off; off >>= 1) vv = fmaxf(vv, __shfl_xor(vv, off, 64));
        if (lane == 0) red[wid * 16 + g] = vv;
    }
    __syncthreads();
    if (tid < 16) {
        float m = red[tid];
#pragma unroll
        for (int w = 1; w < 8; w++) m = fmaxf(m, red[w * 16 + tid]);
        gmax[tid] = m;
    }
    __syncthreads();

    // exp in place + per-head sum
#pragma unroll
    for (int g = 0; g < 16; g++) {
        float mg = gmax[g];
        float p0 = __expf(a[g].x - mg);
        float p1 = __expf(a[g].y - mg);
        a[g].x = p0; a[g].y = p1;
        float vv = p0 + p1;
        for (int off = 32; off; off >>= 1) vv += __shfl_xor(vv, off, 64);
        if (lane == 0) red[wid * 16 + g] = vv;
    }
    __syncthreads();
    if (tid < 16) {
        float s = red[tid];
#pragma unroll
        for (int w = 1; w < 8; w++) s += red[w * 16 + tid];
        gsum[tid] = s;
    }
    __syncthreads();
    if (tid < 256) wwS[tid] = ww[tid] / gsum[tid & 15];   // ww[g,h]/L[h]
    __syncthreads();

    // post-mix + store (fp32 to d_out, bf16 in place over S)
#pragma unroll
    for (int g = 0; g < 16; g++) {
        float wr[16];
        *(float4*)&wr[0]  = *(const float4*)&wwS[g * 16];
        *(float4*)&wr[4]  = *(const float4*)&wwS[g * 16 + 4];
        *(float4*)&wr[8]  = *(const float4*)&wwS[g * 16 + 8];
        *(float4*)&wr[12] = *(const float4*)&wwS[g * 16 + 12];
        float2 o; o.x = bwS[g]; o.y = bwS[g];
#pragma unroll
        for (int h = 0; h < 16; h++) {
            o.x += wr[h] * a[h].x;
            o.y += wr[h] * a[h].y;
        }
        const long long off = base + (long long)g * 1048576;
        *(float2*)(attn_out + off) = o;
        ushort2 bo;
        bo.x = f2bf(o.x); bo.y = f2bf(o.y);
        *(ushort2*)(attn_bf + off) = bo;
    }
}

// ---------------------------------------------------------------------------
// out1[b*1024+n, h*64+d] = sum_m attn_bf[b,h,n,m] * v[b,h,m,d], all bf16.
// Grid: (16, 1, 64). Block 256 = 4 waves; each wave 16 rows x 64 cols.
// ---------------------------------------------------------------------------
__global__ __launch_bounds__(256)
void av_gemm(const u16* __restrict__ attn_bf, const u16* __restrict__ v,
             u16* __restrict__ out1)
{
    __shared__ u16 As[64 * LDSS];
    __shared__ u16 Bs[64 * LDSS];

    const int tid = threadIdx.x;
    const int z = blockIdx.z;   // b*16+h
    const int b = z >> 4, h = z & 15;
    const int m0 = blockIdx.x * 64;
    const u16* Ab = attn_bf + (long long)z * 1048576;
    const u16* Vb = v + (long long)z * 65536;
    const int wid = tid >> 6;
    const int lane = tid & 63;
    const int lr = lane & 15;
    const int quad = lane >> 4;
    const int wm = wid * 16;

    f32x4 acc[4];
#pragma unroll
    for (int j = 0; j < 4; j++)
#pragma unroll
        for (int r = 0; r < 4; r++) acc[j][r] = 0.f;

    const int srow = tid >> 2;        // 0..63
    const int scol = (tid & 3) * 8;
    const int vrow = tid >> 3;        // 0..31 (m within k-tile)
    const int vdb = (tid & 7) * 8;    // d base

    for (int k0 = 0; k0 < 1024; k0 += 32) {
        __syncthreads();
        *(float4*)&As[srow * LDSS + scol] =
            *(const float4*)(Ab + (long long)(m0 + srow) * 1024 + k0 + scol);
        u16 tmp[8];
        *(float4*)tmp = *(const float4*)(Vb + (long long)(k0 + vrow) * 64 + vdb);
#pragma unroll
        for (int j = 0; j < 8; j++) Bs[(vdb + j) * LDSS + vrow] = tmp[j];
        __syncthreads();

        bf16x8 af, bfr[4];
        af = *(const bf16x8*)&As[(wm + lr) * LDSS + quad * 8];
#pragma unroll
        for (int t = 0; t < 4; t++)
            bfr[t] = *(const bf16x8*)&Bs[(t * 16 + lr) * LDSS + quad * 8];
#pragma unroll
        for (int j = 0; j < 4; j++)
            acc[j] = __builtin_amdgcn_mfma_f32_16x16x32_bf16(af, bfr[j], acc[j], 0, 0, 0);
    }

#pragma unroll
    for (int j = 0; j < 4; j++) {
        const int col = h * 64 + j * 16 + lr;
        const int rbase = m0 + wm + quad * 4;
#pragma unroll
        for (int r = 0; r < 4; r++)
            out1[(long long)(b * 1024 + rbase + r) * 1024 + col] = f2bf(acc[j][r]);
    }
}

// ---------------------------------------------------------------------------
extern "C" void kernel_launch(void* const* d_in, const int* in_sizes, int n_in,
                              void* d_out, int out_size, void* d_ws, size_t ws_size,
                              hipStream_t stream)
{
    const float* x      = (const float*)d_in[0];
    const float* qkv_w  = (const float*)d_in[1];
    const float* qkv_b  = (const float*)d_in[2];
    const float* proj_w = (const float*)d_in[3];
    const float* proj_b = (const float*)d_in[4];
    const float* wl     = (const float*)d_in[5];
    const float* bl     = (const float*)d_in[6];
    const float* ww     = (const float*)d_in[7];
    const float* bw     = (const float*)d_in[8];

    float* out      = (float*)d_out;            // [B,N,C] fp32
    float* attn_out = out + 4194304;            // [B,H,N,N] fp32

    u16* ws   = (u16*)d_ws;
    u16* y    = ws;                // 12,582,912 (qkv raw, bf16)
    u16* q    = ws + 12582912;     //  4,194,304
    u16* k    = ws + 16777216;     //  4,194,304
    u16* v    = ws + 20971520;     //  4,194,304
    u16* s    = ws + 25165824;     // 16,777,216 (pre-mix logits; attn_bf aliases it)
    u16* out1 = ws;                // reuse y region (dead after reorder)

    dim3 blk(256);
    // K1: qkv = x @ qkv_w^T + qkv_b   [4096 x 3072 x 1024], fp32 in -> bf16 out
    gemm_nt<float, float, u16><<<dim3(24, 32, 1), blk, 0, stream>>>(
        x, 0, 1024, qkv_w, 0, 1024, y, 0, 3072, qkv_b, 1024);
    // K2: split/scale into q,k,v [B,H,N,HD] bf16
    reorder_qkv<<<dim3(6144), blk, 0, stream>>>(y, q, k, v);
    // K3: per-head scores = q @ k^T  [1024 x 1024 x 64] x 64 heads, bf16
    gemm_nt<u16, u16, u16><<<dim3(8, 8, 64), blk, 0, stream>>>(
        q, 65536, 64, k, 65536, 64, s, 1048576, 1024, nullptr, 64);
    // K4: talking-heads mix + softmax + mix; fp32 attn to d_out, bf16 in place
    mix_softmax<<<dim3(4096), dim3(512), 0, stream>>>(s, attn_out, s, wl, bl, ww, bw);
    // K5: out1 = attn_bf @ v, scattered to [B,N,C] bf16
    av_gemm<<<dim3(16, 1, 64), blk, 0, stream>>>(s, v, out1);
    // K6: out = out1 @ proj_w^T + proj_b  [4096 x 1024 x 1024], fp32 out
    gemm_nt<u16, float, float><<<dim3(8, 32, 1), blk, 0, stream>>>(
        out1, 0, 1024, proj_w, 0, 1024, out, 0, 1024, proj_b, 1024);
}